// Round 2
// baseline (863.249 us; speedup 1.0000x reference)
//
#include <hip/hip_runtime.h>

// SpatialEvoProp — R5: revert R4's 512-thread block (VGPR demotion: 84->40,
// +670MB spill traffic, 201->408us), back to R3 shape (256 thr, lb(256,3),
// budget 170 VGPR) and buy ILP instead of TLP: 2 independent edge-groups per
// iteration, phase-ordered (front A, front B, v-gather A, v-gather B, u A,
// u B, MFMA+epi A, MFMA+epi B) so both groups' random feat-row gathers are
// in flight together. Numerics byte-identical per edge (3-product bf16).

#define DFEAT 64

typedef __attribute__((ext_vector_type(8))) short short8;
typedef __attribute__((ext_vector_type(4))) float floatx4;

__device__ __forceinline__ short bf16h(float x) {
    unsigned u = __float_as_uint(x);
    return (short)((u + 0x7FFFu + ((u >> 16) & 1u)) >> 16);
}
__device__ __forceinline__ float bf16tof(short h) {
    return __uint_as_float(((unsigned)(unsigned short)h) << 16);
}

// count(boundaries < x): analytic seed + shuffle-verified walk vs the real
// table values (lane L holds boundaries[L]); exact for |seed error| <= 2.
__device__ __forceinline__ int bucketize(float x, float bnd) {
    int i = (int)(x * 31.5f);           // boundaries ~ j/31.5
    i = min(max(i, 0), 64);
#pragma unroll
    for (int t = 0; t < 3; ++t) {
        float bi = __shfl(bnd, min(i, 63));
        if (i < 64 && bi < x) ++i;
    }
#pragma unroll
    for (int t = 0; t < 2; ++t) {
        float bim = __shfl(bnd, max(i - 1, 0));
        if (i > 0 && bim >= x) --i;
    }
    return i;
}

// init: zero rst + degree counters, and compute P = embed @ G_w.T ([65,64])
__global__ void k_init(const float* __restrict__ Etab,
                       const float* __restrict__ G, float* __restrict__ P,
                       float* __restrict__ rst, float* __restrict__ degs,
                       int nRst, int nDeg) {
    int i = blockIdx.x * blockDim.x + threadIdx.x;
    if (i < nRst) rst[i] = 0.0f;
    if (i < nDeg) degs[i] = 0.0f;
    if (i < 65 * DFEAT) {
        int b = i >> 6, o = i & 63;
        float a = 0.0f;
#pragma unroll
        for (int m = 0; m < 32; ++m)
            a = fmaf(Etab[b * 32 + m], G[o * 32 + m], a);
        P[i] = a;
    }
}

__global__ void k_deg(const int* __restrict__ src, const int* __restrict__ dst,
                      float* __restrict__ degs, int N, int E) {
    int i = blockIdx.x * blockDim.x + threadIdx.x;
    if (i < E) {
        atomicAdd(&degs[dst[i]], 1.0f);       // in-deg
        atomicAdd(&degs[N + src[i]], 1.0f);   // out-deg
    }
}

#define PPAD 68  // sP row stride: 68%32=4 banks -> b1-dependent bank spread

struct Front {
    int s, d, b1;
    float dsc;
    int ij[5];
    int bj[5];
};

__device__ __forceinline__ void front_phase(
    int g, int m16, int N, int E, const int* __restrict__ src,
    const int* __restrict__ dst, const int* __restrict__ inter,
    const float* __restrict__ loc, const float* __restrict__ degs, float bnd,
    Front& F) {
    const int em = (g << 4) + m16;        // this lane's edge (dup x4)
    const bool act = em < E;              // also false for whole-group overrun
    const int ec = act ? em : 0;

    F.s = src[ec];
    F.d = dst[ec];
    const float2 ls = ((const float2*)loc)[F.s];
    const float2 ld = ((const float2*)loc)[F.d];
    float dsc = rsqrtf(fmaxf(degs[F.d], 1.0f)) *
                rsqrtf(fmaxf(degs[N + F.s], 1.0f));
    F.dsc = act ? dsc : 0.0f;

    float dx = ld.x - ls.x, dy = ld.y - ls.y;
    F.b1 = bucketize(sqrtf(dx * dx + dy * dy), bnd);

#pragma unroll
    for (int j = 0; j < 5; ++j) {
        int id = inter[ec * 5 + j];
        F.ij[j] = id;
        float2 lj = ((const float2*)loc)[id];
        float ex = ls.x - lj.x, ey = ls.y - lj.y;
        F.bj[j] = bucketize(sqrtf(ex * ex + ey * ey), bnd);
    }
}

// v: cat[k>=64] — the 5-row random gather (dominant latency)
__device__ __forceinline__ void vbuild(const Front& F, int quad,
                                       const float* __restrict__ feat,
                                       const float* sP, short8 (&Ah)[4],
                                       short8 (&Al)[4]) {
#pragma unroll
    for (int sl = 0; sl < 2; ++sl) {
        int k0 = sl * 32 + quad * 8;
        float r[8] = {0, 0, 0, 0, 0, 0, 0, 0};
#pragma unroll
        for (int j = 0; j < 5; ++j) {
            const float* fr = feat + (F.ij[j] << 6);
            const float* pr = sP + F.bj[j] * PPAD;
            floatx4 fa = *(const floatx4*)(fr + k0);
            floatx4 fb = *(const floatx4*)(fr + k0 + 4);
            floatx4 pa = *(const floatx4*)(pr + k0);
            floatx4 pb = *(const floatx4*)(pr + k0 + 4);
            r[0] = fmaf(fa.x, pa.x, r[0]);
            r[1] = fmaf(fa.y, pa.y, r[1]);
            r[2] = fmaf(fa.z, pa.z, r[2]);
            r[3] = fmaf(fa.w, pa.w, r[3]);
            r[4] = fmaf(fb.x, pb.x, r[4]);
            r[5] = fmaf(fb.y, pb.y, r[5]);
            r[6] = fmaf(fb.z, pb.z, r[6]);
            r[7] = fmaf(fb.w, pb.w, r[7]);
        }
        short8 h, l;
#pragma unroll
        for (int j = 0; j < 8; ++j) {
            float x = r[j] * 0.2f;
            short hh = bf16h(x);
            h[j] = hh;
            l[j] = bf16h(x - bf16tof(hh));
        }
        Ah[2 + sl] = h;
        Al[2 + sl] = l;
    }
}

// u: cat[k<64] — src feat row * P[b1]
__device__ __forceinline__ void ubuild(const Front& F, int quad,
                                       const float* __restrict__ feat,
                                       const float* sP, short8 (&Ah)[4],
                                       short8 (&Al)[4]) {
    const float* frow = feat + (F.s << 6);
    const float* prow = sP + F.b1 * PPAD;
#pragma unroll
    for (int sl = 0; sl < 2; ++sl) {
        int k0 = sl * 32 + quad * 8;
        floatx4 fa = *(const floatx4*)(frow + k0);
        floatx4 fb = *(const floatx4*)(frow + k0 + 4);
        floatx4 pa = *(const floatx4*)(prow + k0);
        floatx4 pb = *(const floatx4*)(prow + k0 + 4);
        float xs[8] = {fa.x * pa.x, fa.y * pa.y, fa.z * pa.z, fa.w * pa.w,
                       fb.x * pb.x, fb.y * pb.y, fb.z * pb.z, fb.w * pb.w};
        short8 h, l;
#pragma unroll
        for (int j = 0; j < 8; ++j) {
            short hh = bf16h(xs[j]);
            h[j] = hh;
            l[j] = bf16h(xs[j] - bf16tof(hh));
        }
        Ah[sl] = h;
        Al[sl] = l;
    }
}

__device__ __forceinline__ void mfma_epi(const Front& F, int lane, int quad,
                                         int m16, const short8* sWBh,
                                         const short8* sWBl,
                                         const float (&bias4)[4],
                                         float* __restrict__ rst,
                                         short8 (&Ah)[4], short8 (&Al)[4]) {
    floatx4 acc[4] = {{0, 0, 0, 0}, {0, 0, 0, 0}, {0, 0, 0, 0}, {0, 0, 0, 0}};
#pragma unroll
    for (int sl = 0; sl < 4; ++sl) {
#pragma unroll
        for (int nt = 0; nt < 4; ++nt) {
            short8 bh = sWBh[((sl << 2) + nt) * 64 + lane];
            short8 bl = sWBl[((sl << 2) + nt) * 64 + lane];
            acc[nt] = __builtin_amdgcn_mfma_f32_16x16x32_bf16(Ah[sl], bh,
                                                              acc[nt], 0, 0, 0);
            acc[nt] = __builtin_amdgcn_mfma_f32_16x16x32_bf16(Al[sl], bh,
                                                              acc[nt], 0, 0, 0);
            acc[nt] = __builtin_amdgcn_mfma_f32_16x16x32_bf16(Ah[sl], bl,
                                                              acc[nt], 0, 0, 0);
        }
    }
    // epilogue: C row = quad*4+r (edge), col = nt*16+m16 (feature)
#pragma unroll
    for (int r = 0; r < 4; ++r) {
        const int m = (quad << 2) + r;
        const int dm = __shfl(F.d, m);
        const float sc = __shfl(F.dsc, m);
#pragma unroll
        for (int nt = 0; nt < 4; ++nt) {
            float val = (acc[nt][r] + bias4[nt]) * sc;
            atomicAdd(&rst[(dm << 6) + nt * 16 + m16], val);
        }
    }
}

__global__ __launch_bounds__(256, 3) void k_edge(
    const float* __restrict__ feat, const float* __restrict__ loc,
    const float* __restrict__ agg_w, const float* __restrict__ agg_b,
    const float* __restrict__ bnds, const int* __restrict__ src,
    const int* __restrict__ dst, const int* __restrict__ inter,
    const float* __restrict__ P, const float* __restrict__ degs,
    float* __restrict__ rst, int N, int E) {
    const int tid = threadIdx.x;
    const int lane = tid & 63;
    const int wid = tid >> 6;
    const int m16 = lane & 15;
    const int quad = lane >> 4;

    __shared__ float sP[65 * PPAD];     // 17680 B
    __shared__ short8 sWBh[16 * 64];    // 16384 B  B-frag (hi)
    __shared__ short8 sWBl[16 * 64];    // 16384 B  B-frag (lo)

    for (int i = tid; i < 65 * DFEAT; i += 256)
        sP[(i >> 6) * PPAD + (i & 63)] = P[i];

    // B-fragment fill: frag f = slab*4+ntile; lane holds n=nt*16+m16,
    // k = slab*32 + quad*8 + j  (B[k][n] = W^T[k][n] = W[n][k])
    for (int f = wid; f < 16; f += 4) {
        int sl = f >> 2, nt = f & 3;
        const float* wp = agg_w + (nt * 16 + m16) * 128 + sl * 32 + quad * 8;
        floatx4 wa = *(const floatx4*)wp;
        floatx4 wb = *(const floatx4*)(wp + 4);
        float xs[8] = {wa.x, wa.y, wa.z, wa.w, wb.x, wb.y, wb.z, wb.w};
        short8 h, l;
#pragma unroll
        for (int j = 0; j < 8; ++j) {
            short hh = bf16h(xs[j]);
            h[j] = hh;
            l[j] = bf16h(xs[j] - bf16tof(hh));
        }
        sWBh[f * 64 + lane] = h;
        sWBl[f * 64 + lane] = l;
    }

    const float bnd = bnds[lane];
    float bias4[4];
#pragma unroll
    for (int nt = 0; nt < 4; ++nt) bias4[nt] = agg_b[nt * 16 + m16];

    __syncthreads();

    const int nstream = gridDim.x << 2;
    const int wstream = (blockIdx.x << 2) + wid;
    const int ngroups = (E + 15) >> 4;
    const int stride2 = nstream << 1;

    for (int g = wstream; g < ngroups; g += stride2) {
        const int gB = g + nstream;   // may overrun: lanes auto-inactive

        Front FA, FB;
        front_phase(g, m16, N, E, src, dst, inter, loc, degs, bnd, FA);
        front_phase(gB, m16, N, E, src, dst, inter, loc, degs, bnd, FB);

        short8 AhA[4], AlA[4], AhB[4], AlB[4];
        vbuild(FA, quad, feat, sP, AhA, AlA);   // both v-gathers in flight
        vbuild(FB, quad, feat, sP, AhB, AlB);
        ubuild(FA, quad, feat, sP, AhA, AlA);
        ubuild(FB, quad, feat, sP, AhB, AlB);

        mfma_epi(FA, lane, quad, m16, sWBh, sWBl, bias4, rst, AhA, AlA);
        mfma_epi(FB, lane, quad, m16, sWBh, sWBl, bias4, rst, AhB, AlB);
    }
}

extern "C" void kernel_launch(void* const* d_in, const int* in_sizes, int n_in,
                              void* d_out, int out_size, void* d_ws,
                              size_t ws_size, hipStream_t stream) {
    const float* feat  = (const float*)d_in[0];
    const float* loc   = (const float*)d_in[1];
    const float* embed = (const float*)d_in[2];
    const float* G_w   = (const float*)d_in[3];
    const float* agg_w = (const float*)d_in[4];
    const float* agg_b = (const float*)d_in[5];
    const float* bnds  = (const float*)d_in[6];
    const int* src   = (const int*)d_in[7];
    const int* dst   = (const int*)d_in[8];
    const int* inter = (const int*)d_in[9];

    const int N = in_sizes[0] / DFEAT;
    const int E = in_sizes[7];

    float* rst = (float*)d_out;
    float* ws = (float*)d_ws;
    float* degs = ws;               // [2N]: [0,N)=in-deg, [N,2N)=out-deg
    float* P = ws + 2 * (size_t)N;  // [65*64]

    const int nRst = N * DFEAT;
    const int nDeg = 2 * N;

    k_init<<<(nRst + 255) / 256, 256, 0, stream>>>(embed, G_w, P, rst, degs,
                                                   nRst, nDeg);
    k_deg<<<(E + 255) / 256, 256, 0, stream>>>(src, dst, degs, N, E);
    // LDS 50448 B/block -> 3 blocks/CU; 768 blocks = exactly resident
    k_edge<<<768, 256, 0, stream>>>(feat, loc, agg_w, agg_b, bnds, src, dst,
                                    inter, P, degs, rst, N, E);
}

// Round 3
// 330.909 us; speedup vs baseline: 2.6087x; 2.6087x over previous
//
#include <hip/hip_runtime.h>

// SpatialEvoProp — R6: cut bytes through the ~3.2 TB/s L2-miss ceiling.
// Evidence: R3 (3.16 TB/s) and R4 (3.22 TB/s, different traffic mix) both pin
// at the same fabric/L3 BW. Dominant stream = random gather of 6 fp32 feat
// rows/edge (~450MB/dispatch after L2). Change: bf16 shadow of feat (6.4MB,
// built in k_init); the 5 inter-row gathers read it (half the bytes, ~2x the
// L2 hit rate). src row stays fp32 (u-part precision). Body otherwise
// byte-identical to R3 (84 VGPR, no spills). R4 (512thr) and R5 (2x ILP)
// both demoted registers — do not revisit.

#define DFEAT 64

typedef __attribute__((ext_vector_type(8))) short short8;
typedef __attribute__((ext_vector_type(4))) float floatx4;

__device__ __forceinline__ short bf16h(float x) {
    unsigned u = __float_as_uint(x);
    return (short)((u + 0x7FFFu + ((u >> 16) & 1u)) >> 16);
}
__device__ __forceinline__ float bf16tof(short h) {
    return __uint_as_float(((unsigned)(unsigned short)h) << 16);
}

// count(boundaries < x): analytic seed + shuffle-verified walk vs the real
// table values (lane L holds boundaries[L]); exact for |seed error| <= 2.
__device__ __forceinline__ int bucketize(float x, float bnd) {
    int i = (int)(x * 31.5f);           // boundaries ~ j/31.5
    i = min(max(i, 0), 64);
#pragma unroll
    for (int t = 0; t < 3; ++t) {
        float bi = __shfl(bnd, min(i, 63));
        if (i < 64 && bi < x) ++i;
    }
#pragma unroll
    for (int t = 0; t < 2; ++t) {
        float bim = __shfl(bnd, max(i - 1, 0));
        if (i > 0 && bim >= x) --i;
    }
    return i;
}

// init: zero rst + degree counters, P = embed @ G_w.T ([65,64]),
// and featB = bf16(feat) (same index range as rst: N*64 elements).
__global__ void k_init(const float* __restrict__ Etab,
                       const float* __restrict__ G, float* __restrict__ P,
                       float* __restrict__ rst, float* __restrict__ degs,
                       const float* __restrict__ feat,
                       short* __restrict__ featB, int nRst, int nDeg) {
    int i = blockIdx.x * blockDim.x + threadIdx.x;
    if (i < nRst) {
        rst[i] = 0.0f;
        if (featB) featB[i] = bf16h(feat[i]);
    }
    if (i < nDeg) degs[i] = 0.0f;
    if (i < 65 * DFEAT) {
        int b = i >> 6, o = i & 63;
        float a = 0.0f;
#pragma unroll
        for (int m = 0; m < 32; ++m)
            a = fmaf(Etab[b * 32 + m], G[o * 32 + m], a);
        P[i] = a;
    }
}

__global__ void k_deg(const int* __restrict__ src, const int* __restrict__ dst,
                      float* __restrict__ degs, int N, int E) {
    int i = blockIdx.x * blockDim.x + threadIdx.x;
    if (i < E) {
        atomicAdd(&degs[dst[i]], 1.0f);       // in-deg
        atomicAdd(&degs[N + src[i]], 1.0f);   // out-deg
    }
}

#define PPAD 68  // sP row stride: 68%32=4 banks -> b1-dependent bank spread

__global__ __launch_bounds__(256, 3) void k_edge(
    const float* __restrict__ feat, const short* __restrict__ featB,
    const float* __restrict__ loc, const float* __restrict__ agg_w,
    const float* __restrict__ agg_b, const float* __restrict__ bnds,
    const int* __restrict__ src, const int* __restrict__ dst,
    const int* __restrict__ inter, const float* __restrict__ P,
    const float* __restrict__ degs, float* __restrict__ rst, int N, int E) {
    const int tid = threadIdx.x;
    const int lane = tid & 63;
    const int wid = tid >> 6;
    const int m16 = lane & 15;
    const int quad = lane >> 4;

    __shared__ float sP[65 * PPAD];     // 17680 B
    __shared__ short8 sWBh[16 * 64];    // 16384 B  B-frag (hi)
    __shared__ short8 sWBl[16 * 64];    // 16384 B  B-frag (lo)

    for (int i = tid; i < 65 * DFEAT; i += 256)
        sP[(i >> 6) * PPAD + (i & 63)] = P[i];

    // B-fragment fill: frag f = slab*4+ntile; lane holds n=nt*16+m16,
    // k = slab*32 + quad*8 + j  (B[k][n] = W^T[k][n] = W[n][k])
    for (int f = wid; f < 16; f += 4) {
        int sl = f >> 2, nt = f & 3;
        const float* wp = agg_w + (nt * 16 + m16) * 128 + sl * 32 + quad * 8;
        floatx4 wa = *(const floatx4*)wp;
        floatx4 wb = *(const floatx4*)(wp + 4);
        float xs[8] = {wa.x, wa.y, wa.z, wa.w, wb.x, wb.y, wb.z, wb.w};
        short8 h, l;
#pragma unroll
        for (int j = 0; j < 8; ++j) {
            short hh = bf16h(xs[j]);
            h[j] = hh;
            l[j] = bf16h(xs[j] - bf16tof(hh));
        }
        sWBh[f * 64 + lane] = h;
        sWBl[f * 64 + lane] = l;
    }

    const float bnd = bnds[lane];
    float bias4[4];
#pragma unroll
    for (int nt = 0; nt < 4; ++nt) bias4[nt] = agg_b[nt * 16 + m16];

    __syncthreads();

    const int nstream = gridDim.x << 2;
    const int wstream = (blockIdx.x << 2) + wid;
    const int ngroups = (E + 15) >> 4;

    for (int g = wstream; g < ngroups; g += nstream) {
        const int em = (g << 4) + m16;        // this lane's edge (dup x4)
        const bool act = em < E;
        const int ec = act ? em : 0;

        const int s = src[ec];
        const int d = dst[ec];
        const float2 ls = ((const float2*)loc)[s];
        const float2 ld = ((const float2*)loc)[d];
        float dsc = rsqrtf(fmaxf(degs[d], 1.0f)) *
                    rsqrtf(fmaxf(degs[N + s], 1.0f));
        if (!act) dsc = 0.0f;

        float dx = ld.x - ls.x, dy = ld.y - ls.y;
        const int b1 = bucketize(sqrtf(dx * dx + dy * dy), bnd);

        int ij[5], bj[5];
#pragma unroll
        for (int j = 0; j < 5; ++j) {
            int id = inter[ec * 5 + j];
            ij[j] = id;
            float2 lj = ((const float2*)loc)[id];
            float ex = ls.x - lj.x, ey = ls.y - lj.y;
            bj[j] = bucketize(sqrtf(ex * ex + ey * ey), bnd);
        }

        // ---- build A fragments in registers -------------------------------
        short8 Ah[4], Al[4];
        {
            const float* frow = feat + (s << 6);
            const float* prow = sP + b1 * PPAD;
#pragma unroll
            for (int sl = 0; sl < 2; ++sl) {      // u: cat[k<64], fp32 src row
                int k0 = sl * 32 + quad * 8;
                floatx4 fa = *(const floatx4*)(frow + k0);
                floatx4 fb = *(const floatx4*)(frow + k0 + 4);
                floatx4 pa = *(const floatx4*)(prow + k0);
                floatx4 pb = *(const floatx4*)(prow + k0 + 4);
                float xs[8] = {fa.x * pa.x, fa.y * pa.y, fa.z * pa.z,
                               fa.w * pa.w, fb.x * pb.x, fb.y * pb.y,
                               fb.z * pb.z, fb.w * pb.w};
                short8 h, l;
#pragma unroll
                for (int j = 0; j < 8; ++j) {
                    short hh = bf16h(xs[j]);
                    h[j] = hh;
                    l[j] = bf16h(xs[j] - bf16tof(hh));
                }
                Ah[sl] = h;
                Al[sl] = l;
            }
        }
#pragma unroll
        for (int sl = 0; sl < 2; ++sl) {          // v: cat[k>=64], bf16 gathers
            int k0 = sl * 32 + quad * 8;
            float r[8] = {0, 0, 0, 0, 0, 0, 0, 0};
            if (featB) {
#pragma unroll
                for (int j = 0; j < 5; ++j) {
                    const short8 fv =
                        *(const short8*)(featB + (ij[j] << 6) + k0);
                    const float* pr = sP + bj[j] * PPAD;
                    floatx4 pa = *(const floatx4*)(pr + k0);
                    floatx4 pb = *(const floatx4*)(pr + k0 + 4);
                    r[0] = fmaf(bf16tof(fv[0]), pa.x, r[0]);
                    r[1] = fmaf(bf16tof(fv[1]), pa.y, r[1]);
                    r[2] = fmaf(bf16tof(fv[2]), pa.z, r[2]);
                    r[3] = fmaf(bf16tof(fv[3]), pa.w, r[3]);
                    r[4] = fmaf(bf16tof(fv[4]), pb.x, r[4]);
                    r[5] = fmaf(bf16tof(fv[5]), pb.y, r[5]);
                    r[6] = fmaf(bf16tof(fv[6]), pb.z, r[6]);
                    r[7] = fmaf(bf16tof(fv[7]), pb.w, r[7]);
                }
            } else {                               // fallback: fp32 gathers
#pragma unroll
                for (int j = 0; j < 5; ++j) {
                    const float* fr = feat + (ij[j] << 6);
                    const float* pr = sP + bj[j] * PPAD;
                    floatx4 fa = *(const floatx4*)(fr + k0);
                    floatx4 fb = *(const floatx4*)(fr + k0 + 4);
                    floatx4 pa = *(const floatx4*)(pr + k0);
                    floatx4 pb = *(const floatx4*)(pr + k0 + 4);
                    r[0] = fmaf(fa.x, pa.x, r[0]);
                    r[1] = fmaf(fa.y, pa.y, r[1]);
                    r[2] = fmaf(fa.z, pa.z, r[2]);
                    r[3] = fmaf(fa.w, pa.w, r[3]);
                    r[4] = fmaf(fb.x, pb.x, r[4]);
                    r[5] = fmaf(fb.y, pb.y, r[5]);
                    r[6] = fmaf(fb.z, pb.z, r[6]);
                    r[7] = fmaf(fb.w, pb.w, r[7]);
                }
            }
            short8 h, l;
#pragma unroll
            for (int j = 0; j < 8; ++j) {
                float x = r[j] * 0.2f;
                short hh = bf16h(x);
                h[j] = hh;
                l[j] = bf16h(x - bf16tof(hh));
            }
            Ah[2 + sl] = h;
            Al[2 + sl] = l;
        }

        // ---- MFMA: 4 k-slabs x 4 n-tiles x 3 products ---------------------
        floatx4 acc[4] = {{0, 0, 0, 0}, {0, 0, 0, 0}, {0, 0, 0, 0}, {0, 0, 0, 0}};
#pragma unroll
        for (int sl = 0; sl < 4; ++sl) {
#pragma unroll
            for (int nt = 0; nt < 4; ++nt) {
                short8 bh = sWBh[((sl << 2) + nt) * 64 + lane];
                short8 bl = sWBl[((sl << 2) + nt) * 64 + lane];
                acc[nt] = __builtin_amdgcn_mfma_f32_16x16x32_bf16(
                    Ah[sl], bh, acc[nt], 0, 0, 0);
                acc[nt] = __builtin_amdgcn_mfma_f32_16x16x32_bf16(
                    Al[sl], bh, acc[nt], 0, 0, 0);
                acc[nt] = __builtin_amdgcn_mfma_f32_16x16x32_bf16(
                    Ah[sl], bl, acc[nt], 0, 0, 0);
            }
        }

        // ---- epilogue: C row = quad*4+r (edge), col = nt*16+m16 (feature) -
#pragma unroll
        for (int r = 0; r < 4; ++r) {
            const int m = (quad << 2) + r;
            const int dm = __shfl(d, m);
            const float sc = __shfl(dsc, m);
#pragma unroll
            for (int nt = 0; nt < 4; ++nt) {
                float val = (acc[nt][r] + bias4[nt]) * sc;
                atomicAdd(&rst[(dm << 6) + nt * 16 + m16], val);
            }
        }
    }
}

extern "C" void kernel_launch(void* const* d_in, const int* in_sizes, int n_in,
                              void* d_out, int out_size, void* d_ws,
                              size_t ws_size, hipStream_t stream) {
    const float* feat  = (const float*)d_in[0];
    const float* loc   = (const float*)d_in[1];
    const float* embed = (const float*)d_in[2];
    const float* G_w   = (const float*)d_in[3];
    const float* agg_w = (const float*)d_in[4];
    const float* agg_b = (const float*)d_in[5];
    const float* bnds  = (const float*)d_in[6];
    const int* src   = (const int*)d_in[7];
    const int* dst   = (const int*)d_in[8];
    const int* inter = (const int*)d_in[9];

    const int N = in_sizes[0] / DFEAT;
    const int E = in_sizes[7];

    float* rst = (float*)d_out;
    float* ws = (float*)d_ws;
    float* degs = ws;               // [2N]: [0,N)=in-deg, [N,2N)=out-deg
    float* P = ws + 2 * (size_t)N;  // [65*64]

    // bf16 shadow of feat, 16B-aligned, after P
    size_t fixed_bytes = (2 * (size_t)N + 65 * DFEAT) * sizeof(float);
    size_t fb_off = (fixed_bytes + 15) & ~(size_t)15;
    size_t need = fb_off + (size_t)N * DFEAT * sizeof(short);
    short* featB = (ws_size >= need) ? (short*)((char*)d_ws + fb_off) : nullptr;

    const int nRst = N * DFEAT;
    const int nDeg = 2 * N;

    k_init<<<(nRst + 255) / 256, 256, 0, stream>>>(embed, G_w, P, rst, degs,
                                                   feat, featB, nRst, nDeg);
    k_deg<<<(E + 255) / 256, 256, 0, stream>>>(src, dst, degs, N, E);
    // LDS 50448 B/block -> 3 blocks/CU; 768 blocks = exactly resident
    k_edge<<<768, 256, 0, stream>>>(feat, featB, loc, agg_w, agg_b, bnds, src,
                                    dst, inter, P, degs, rst, N, E);
}

// Round 4
// 329.356 us; speedup vs baseline: 2.6210x; 1.0047x over previous
//
#include <hip/hip_runtime.h>

// SpatialEvoProp — R7: unified fp16 gather table.
// R6 lesson: splitting feat(fp32,src)/featB(bf16,inter) BROKE line sharing
// between the 6 row streams and grew L2 footprint to 19.2MB -> FETCH rose
// 481->554MB, k_edge 201->229us. All rounds pin at ~3.2-3.3 TB/s L2-miss BW
// (fabric ceiling), so bytes are the lever: ALL six streams now gather one
// 6.4MB fp16 table featH (near-L2-resident/XCD; fp32 feat untouched in
// k_edge). fp16 mantissa (2^-12) ~8x finer than bf16 -> absmax back near
// R3's 2^-8. Body/occupancy identical to R3 (84 VGPR, lb(256,3)).
// Poisoned levers: 512-thr blocks (R4: VGPR demotion), 2x manual ILP (R5:
// scratch + occupancy collapse). Do not revisit.

#define DFEAT 64

typedef __attribute__((ext_vector_type(8))) short short8;
typedef __attribute__((ext_vector_type(8))) _Float16 half8;
typedef __attribute__((ext_vector_type(4))) float floatx4;

__device__ __forceinline__ short bf16h(float x) {
    unsigned u = __float_as_uint(x);
    return (short)((u + 0x7FFFu + ((u >> 16) & 1u)) >> 16);
}
__device__ __forceinline__ float bf16tof(short h) {
    return __uint_as_float(((unsigned)(unsigned short)h) << 16);
}

// count(boundaries < x): analytic seed + shuffle-verified walk vs the real
// table values (lane L holds boundaries[L]); exact for |seed error| <= 2.
__device__ __forceinline__ int bucketize(float x, float bnd) {
    int i = (int)(x * 31.5f);           // boundaries ~ j/31.5
    i = min(max(i, 0), 64);
#pragma unroll
    for (int t = 0; t < 3; ++t) {
        float bi = __shfl(bnd, min(i, 63));
        if (i < 64 && bi < x) ++i;
    }
#pragma unroll
    for (int t = 0; t < 2; ++t) {
        float bim = __shfl(bnd, max(i - 1, 0));
        if (i > 0 && bim >= x) --i;
    }
    return i;
}

// init: zero rst + degree counters, P = embed @ G_w.T ([65,64]),
// and featH = fp16(feat) (same index range as rst: N*64 elements).
__global__ void k_init(const float* __restrict__ Etab,
                       const float* __restrict__ G, float* __restrict__ P,
                       float* __restrict__ rst, float* __restrict__ degs,
                       const float* __restrict__ feat,
                       _Float16* __restrict__ featH, int nRst, int nDeg) {
    int i = blockIdx.x * blockDim.x + threadIdx.x;
    if (i < nRst) {
        rst[i] = 0.0f;
        if (featH) featH[i] = (_Float16)feat[i];
    }
    if (i < nDeg) degs[i] = 0.0f;
    if (i < 65 * DFEAT) {
        int b = i >> 6, o = i & 63;
        float a = 0.0f;
#pragma unroll
        for (int m = 0; m < 32; ++m)
            a = fmaf(Etab[b * 32 + m], G[o * 32 + m], a);
        P[i] = a;
    }
}

__global__ void k_deg(const int* __restrict__ src, const int* __restrict__ dst,
                      float* __restrict__ degs, int N, int E) {
    int i = blockIdx.x * blockDim.x + threadIdx.x;
    if (i < E) {
        atomicAdd(&degs[dst[i]], 1.0f);       // in-deg
        atomicAdd(&degs[N + src[i]], 1.0f);   // out-deg
    }
}

#define PPAD 68  // sP row stride: 68%32=4 banks -> b1-dependent bank spread

__global__ __launch_bounds__(256, 3) void k_edge(
    const float* __restrict__ feat, const _Float16* __restrict__ featH,
    const float* __restrict__ loc, const float* __restrict__ agg_w,
    const float* __restrict__ agg_b, const float* __restrict__ bnds,
    const int* __restrict__ src, const int* __restrict__ dst,
    const int* __restrict__ inter, const float* __restrict__ P,
    const float* __restrict__ degs, float* __restrict__ rst, int N, int E) {
    const int tid = threadIdx.x;
    const int lane = tid & 63;
    const int wid = tid >> 6;
    const int m16 = lane & 15;
    const int quad = lane >> 4;

    __shared__ float sP[65 * PPAD];     // 17680 B
    __shared__ short8 sWBh[16 * 64];    // 16384 B  B-frag (hi)
    __shared__ short8 sWBl[16 * 64];    // 16384 B  B-frag (lo)

    for (int i = tid; i < 65 * DFEAT; i += 256)
        sP[(i >> 6) * PPAD + (i & 63)] = P[i];

    // B-fragment fill: frag f = slab*4+ntile; lane holds n=nt*16+m16,
    // k = slab*32 + quad*8 + j  (B[k][n] = W^T[k][n] = W[n][k])
    for (int f = wid; f < 16; f += 4) {
        int sl = f >> 2, nt = f & 3;
        const float* wp = agg_w + (nt * 16 + m16) * 128 + sl * 32 + quad * 8;
        floatx4 wa = *(const floatx4*)wp;
        floatx4 wb = *(const floatx4*)(wp + 4);
        float xs[8] = {wa.x, wa.y, wa.z, wa.w, wb.x, wb.y, wb.z, wb.w};
        short8 h, l;
#pragma unroll
        for (int j = 0; j < 8; ++j) {
            short hh = bf16h(xs[j]);
            h[j] = hh;
            l[j] = bf16h(xs[j] - bf16tof(hh));
        }
        sWBh[f * 64 + lane] = h;
        sWBl[f * 64 + lane] = l;
    }

    const float bnd = bnds[lane];
    float bias4[4];
#pragma unroll
    for (int nt = 0; nt < 4; ++nt) bias4[nt] = agg_b[nt * 16 + m16];

    __syncthreads();

    const int nstream = gridDim.x << 2;
    const int wstream = (blockIdx.x << 2) + wid;
    const int ngroups = (E + 15) >> 4;

    for (int g = wstream; g < ngroups; g += nstream) {
        const int em = (g << 4) + m16;        // this lane's edge (dup x4)
        const bool act = em < E;
        const int ec = act ? em : 0;

        const int s = src[ec];
        const int d = dst[ec];
        const float2 ls = ((const float2*)loc)[s];
        const float2 ld = ((const float2*)loc)[d];
        float dsc = rsqrtf(fmaxf(degs[d], 1.0f)) *
                    rsqrtf(fmaxf(degs[N + s], 1.0f));
        if (!act) dsc = 0.0f;

        float dx = ld.x - ls.x, dy = ld.y - ls.y;
        const int b1 = bucketize(sqrtf(dx * dx + dy * dy), bnd);

        int ij[5], bj[5];
#pragma unroll
        for (int j = 0; j < 5; ++j) {
            int id = inter[ec * 5 + j];
            ij[j] = id;
            float2 lj = ((const float2*)loc)[id];
            float ex = ls.x - lj.x, ey = ls.y - lj.y;
            bj[j] = bucketize(sqrtf(ex * ex + ey * ey), bnd);
        }

        // ---- build A fragments in registers -------------------------------
        short8 Ah[4], Al[4];
        if (featH) {
            // u: cat[k<64], fp16 src row (one 16B load per slab)
            const _Float16* frow = featH + (s << 6);
            const float* prow = sP + b1 * PPAD;
#pragma unroll
            for (int sl = 0; sl < 2; ++sl) {
                int k0 = sl * 32 + quad * 8;
                half8 f1 = *(const half8*)(frow + k0);
                floatx4 pa = *(const floatx4*)(prow + k0);
                floatx4 pb = *(const floatx4*)(prow + k0 + 4);
                float xs[8] = {(float)f1[0] * pa.x, (float)f1[1] * pa.y,
                               (float)f1[2] * pa.z, (float)f1[3] * pa.w,
                               (float)f1[4] * pb.x, (float)f1[5] * pb.y,
                               (float)f1[6] * pb.z, (float)f1[7] * pb.w};
                short8 h, l;
#pragma unroll
                for (int j = 0; j < 8; ++j) {
                    short hh = bf16h(xs[j]);
                    h[j] = hh;
                    l[j] = bf16h(xs[j] - bf16tof(hh));
                }
                Ah[sl] = h;
                Al[sl] = l;
            }
            // v: cat[k>=64], fp16 gathers of 5 inter rows
#pragma unroll
            for (int sl = 0; sl < 2; ++sl) {
                int k0 = sl * 32 + quad * 8;
                float r[8] = {0, 0, 0, 0, 0, 0, 0, 0};
#pragma unroll
                for (int j = 0; j < 5; ++j) {
                    const half8 fv = *(const half8*)(featH + (ij[j] << 6) + k0);
                    const float* pr = sP + bj[j] * PPAD;
                    floatx4 pa = *(const floatx4*)(pr + k0);
                    floatx4 pb = *(const floatx4*)(pr + k0 + 4);
                    r[0] = fmaf((float)fv[0], pa.x, r[0]);
                    r[1] = fmaf((float)fv[1], pa.y, r[1]);
                    r[2] = fmaf((float)fv[2], pa.z, r[2]);
                    r[3] = fmaf((float)fv[3], pa.w, r[3]);
                    r[4] = fmaf((float)fv[4], pb.x, r[4]);
                    r[5] = fmaf((float)fv[5], pb.y, r[5]);
                    r[6] = fmaf((float)fv[6], pb.z, r[6]);
                    r[7] = fmaf((float)fv[7], pb.w, r[7]);
                }
                short8 h, l;
#pragma unroll
                for (int j = 0; j < 8; ++j) {
                    float x = r[j] * 0.2f;
                    short hh = bf16h(x);
                    h[j] = hh;
                    l[j] = bf16h(x - bf16tof(hh));
                }
                Ah[2 + sl] = h;
                Al[2 + sl] = l;
            }
        } else {
            // fallback (no workspace): R3 fp32 path
            const float* frow = feat + (s << 6);
            const float* prow = sP + b1 * PPAD;
#pragma unroll
            for (int sl = 0; sl < 2; ++sl) {
                int k0 = sl * 32 + quad * 8;
                floatx4 fa = *(const floatx4*)(frow + k0);
                floatx4 fb = *(const floatx4*)(frow + k0 + 4);
                floatx4 pa = *(const floatx4*)(prow + k0);
                floatx4 pb = *(const floatx4*)(prow + k0 + 4);
                float xs[8] = {fa.x * pa.x, fa.y * pa.y, fa.z * pa.z,
                               fa.w * pa.w, fb.x * pb.x, fb.y * pb.y,
                               fb.z * pb.z, fb.w * pb.w};
                short8 h, l;
#pragma unroll
                for (int j = 0; j < 8; ++j) {
                    short hh = bf16h(xs[j]);
                    h[j] = hh;
                    l[j] = bf16h(xs[j] - bf16tof(hh));
                }
                Ah[sl] = h;
                Al[sl] = l;
            }
#pragma unroll
            for (int sl = 0; sl < 2; ++sl) {
                int k0 = sl * 32 + quad * 8;
                float r[8] = {0, 0, 0, 0, 0, 0, 0, 0};
#pragma unroll
                for (int j = 0; j < 5; ++j) {
                    const float* fr = feat + (ij[j] << 6);
                    const float* pr = sP + bj[j] * PPAD;
                    floatx4 fa = *(const floatx4*)(fr + k0);
                    floatx4 fb = *(const floatx4*)(fr + k0 + 4);
                    floatx4 pa = *(const floatx4*)(pr + k0);
                    floatx4 pb = *(const floatx4*)(pr + k0 + 4);
                    r[0] = fmaf(fa.x, pa.x, r[0]);
                    r[1] = fmaf(fa.y, pa.y, r[1]);
                    r[2] = fmaf(fa.z, pa.z, r[2]);
                    r[3] = fmaf(fa.w, pa.w, r[3]);
                    r[4] = fmaf(fb.x, pb.x, r[4]);
                    r[5] = fmaf(fb.y, pb.y, r[5]);
                    r[6] = fmaf(fb.z, pb.z, r[6]);
                    r[7] = fmaf(fb.w, pb.w, r[7]);
                }
                short8 h, l;
#pragma unroll
                for (int j = 0; j < 8; ++j) {
                    float x = r[j] * 0.2f;
                    short hh = bf16h(x);
                    h[j] = hh;
                    l[j] = bf16h(x - bf16tof(hh));
                }
                Ah[2 + sl] = h;
                Al[2 + sl] = l;
            }
        }

        // ---- MFMA: 4 k-slabs x 4 n-tiles x 3 products ---------------------
        floatx4 acc[4] = {{0, 0, 0, 0}, {0, 0, 0, 0}, {0, 0, 0, 0}, {0, 0, 0, 0}};
#pragma unroll
        for (int sl = 0; sl < 4; ++sl) {
#pragma unroll
            for (int nt = 0; nt < 4; ++nt) {
                short8 bh = sWBh[((sl << 2) + nt) * 64 + lane];
                short8 bl = sWBl[((sl << 2) + nt) * 64 + lane];
                acc[nt] = __builtin_amdgcn_mfma_f32_16x16x32_bf16(
                    Ah[sl], bh, acc[nt], 0, 0, 0);
                acc[nt] = __builtin_amdgcn_mfma_f32_16x16x32_bf16(
                    Al[sl], bh, acc[nt], 0, 0, 0);
                acc[nt] = __builtin_amdgcn_mfma_f32_16x16x32_bf16(
                    Ah[sl], bl, acc[nt], 0, 0, 0);
            }
        }

        // ---- epilogue: C row = quad*4+r (edge), col = nt*16+m16 (feature) -
#pragma unroll
        for (int r = 0; r < 4; ++r) {
            const int m = (quad << 2) + r;
            const int dm = __shfl(d, m);
            const float sc = __shfl(dsc, m);
#pragma unroll
            for (int nt = 0; nt < 4; ++nt) {
                float val = (acc[nt][r] + bias4[nt]) * sc;
                atomicAdd(&rst[(dm << 6) + nt * 16 + m16], val);
            }
        }
    }
}

extern "C" void kernel_launch(void* const* d_in, const int* in_sizes, int n_in,
                              void* d_out, int out_size, void* d_ws,
                              size_t ws_size, hipStream_t stream) {
    const float* feat  = (const float*)d_in[0];
    const float* loc   = (const float*)d_in[1];
    const float* embed = (const float*)d_in[2];
    const float* G_w   = (const float*)d_in[3];
    const float* agg_w = (const float*)d_in[4];
    const float* agg_b = (const float*)d_in[5];
    const float* bnds  = (const float*)d_in[6];
    const int* src   = (const int*)d_in[7];
    const int* dst   = (const int*)d_in[8];
    const int* inter = (const int*)d_in[9];

    const int N = in_sizes[0] / DFEAT;
    const int E = in_sizes[7];

    float* rst = (float*)d_out;
    float* ws = (float*)d_ws;
    float* degs = ws;               // [2N]: [0,N)=in-deg, [N,2N)=out-deg
    float* P = ws + 2 * (size_t)N;  // [65*64]

    // fp16 shadow of feat, 16B-aligned, after P
    size_t fixed_bytes = (2 * (size_t)N + 65 * DFEAT) * sizeof(float);
    size_t fb_off = (fixed_bytes + 15) & ~(size_t)15;
    size_t need = fb_off + (size_t)N * DFEAT * sizeof(_Float16);
    _Float16* featH =
        (ws_size >= need) ? (_Float16*)((char*)d_ws + fb_off) : nullptr;

    const int nRst = N * DFEAT;
    const int nDeg = 2 * N;

    k_init<<<(nRst + 255) / 256, 256, 0, stream>>>(embed, G_w, P, rst, degs,
                                                   feat, featH, nRst, nDeg);
    k_deg<<<(E + 255) / 256, 256, 0, stream>>>(src, dst, degs, N, E);
    // LDS 50448 B/block -> 3 blocks/CU; 768 blocks = exactly resident
    k_edge<<<768, 256, 0, stream>>>(feat, featH, loc, agg_w, agg_b, bnds, src,
                                    dst, inter, P, degs, rst, N, E);
}